// Round 1
// baseline (108.277 us; speedup 1.0000x reference)
//
#include <hip/hip_runtime.h>
#include <math.h>

#define N_SAMP 8192
#define BLK 128

constexpr float PI_F = 3.14159265358979323846f;
// C-band wavenumber, computed in double then rounded to f32 (matches weak-typed
// Python float -> f32 promotion in the reference).
constexpr float K_WAVE_F = (float)(2.0 * 3.14159265358979323846 * 5.405e9 / 2.998e8);

__device__ __forceinline__ float rcp_f(float x)     { return __builtin_amdgcn_rcpf(x); }
__device__ __forceinline__ float sigmoid_f(float x) { return rcp_f(1.0f + __expf(-x)); }
// 1 - 2/(e^{2x}+1): exact saturation at +-inf, ~1e-7 abs error
__device__ __forceinline__ float tanh_f(float x)    { return 1.0f - 2.0f * rcp_f(__expf(2.0f * x) + 1.0f); }

__global__ __launch_bounds__(BLK) void pinn_fused(
    const float* __restrict__ X, const float* __restrict__ theta_deg,
    const float* __restrict__ Wp1, const float* __restrict__ bp1,
    const float* __restrict__ Wp2, const float* __restrict__ bp2,
    const float* __restrict__ Wp3, const float* __restrict__ bp3,
    const float* __restrict__ Wc1, const float* __restrict__ bc1,
    const float* __restrict__ Wc2, const float* __restrict__ bc2,
    const float* __restrict__ Wc3, const float* __restrict__ bc3,
    const float* __restrict__ nb_raw, const float* __restrict__ nl_raw,
    const float* __restrict__ so_raw, const float* __restrict__ mg_raw,
    const float* __restrict__ s_raw, float* __restrict__ out)
{
  // LDS: weights for both MLPs. Pads chosen so the two MLPs' blocks differ in
  // bank offset (m-streams land on different banks -> <=2-way broadcast = free).
  __shared__ float W1s[2][520];   // [m][i*64+k], 512 used + 8 pad (bank shift 8)
  __shared__ float W2s[2][4112];  // [m][k*64+j], 4096 used + 16 pad (bank shift 16)
  __shared__ float W3s[2][64];
  __shared__ float b1s[2][64];
  __shared__ float b2s[2][64];
  __shared__ float b3s[2];
  __shared__ float h1s[BLK][36];  // per-thread 32 h1 values, padded row (16B-aligned)

  const int tid  = threadIdx.x;
  const int lane = tid & 63;

  // ---- stage weights to LDS ----
  for (int i = tid; i < 512; i += BLK) { W1s[0][i] = Wp1[i]; W1s[1][i] = Wc1[i]; }
  {
    float4* d0 = reinterpret_cast<float4*>(&W2s[0][0]);
    float4* d1 = reinterpret_cast<float4*>(&W2s[1][0]);
    const float4* s0 = reinterpret_cast<const float4*>(Wp2);
    const float4* s1 = reinterpret_cast<const float4*>(Wc2);
    for (int i = tid; i < 1024; i += BLK) { d0[i] = s0[i]; d1[i] = s1[i]; }
  }
  if (tid < 64) {
    W3s[0][tid] = Wp3[tid]; W3s[1][tid] = Wc3[tid];
    b1s[0][tid] = bp1[tid]; b1s[1][tid] = bc1[tid];
    b2s[0][tid] = bp2[tid]; b2s[1][tid] = bc2[tid];
    if (tid < 2) b3s[tid] = (tid == 0) ? bp3[0] : bc3[0];
  }

  // ---- theta-moments of the orientation pdf (phi-integral done analytically) ----
  // crown_vv = Kv^2 (ct^4 S1 + 3 ct^2 st^2 S2 + 0.375 st^4 S3)
  // crown_vh = Kv^2 (0.5 ct^2 S2 + 0.125 st^2 S3)
  const float sig_o  = (10.0f + 70.0f * sigmoid_f(so_raw[0])) * (PI_F / 180.0f);
  const float inv2s2 = 1.0f / (2.0f * sig_o * sig_o);
  float p0 = 0.f, p1 = 0.f, p2 = 0.f, p3 = 0.f;
#pragma unroll
  for (int r = 0; r < 2; ++r) {
    const int   t  = lane + 64 * r;
    const float th = (float)t * (PI_F * 0.5f / 127.0f);
    const float snt = sinf(th), cst = cosf(th);
    const float d  = th - PI_F * 0.25f;
    const float pdf = __expf(-d * d * inv2s2) * snt;
    const float c2 = cst * cst, s2 = snt * snt;
    p0 += pdf; p1 += pdf * c2 * c2; p2 += pdf * c2 * s2; p3 += pdf * s2 * s2;
  }
#pragma unroll
  for (int off = 1; off < 64; off <<= 1) {
    p0 += __shfl_xor(p0, off);
    p1 += __shfl_xor(p1, off);
    p2 += __shfl_xor(p2, off);
    p3 += __shfl_xor(p3, off);
  }
  const float invp0 = 1.0f / p0;
  const float S1 = p1 * invp0, S2 = p2 * invp0, S3 = p3 * invp0;

  // ---- global scalar parameters ----
  const float Nb   = exp10f(2.0f + 3.0f * sigmoid_f(nb_raw[0]));
  const float Nl   = exp10f(3.0f + 3.0f * sigmoid_f(nl_raw[0]));
  const float mg   = 0.05f + 0.75f * sigmoid_f(mg_raw[0]);
  const float smr  = 0.01f * (0.5f + 5.5f * sigmoid_f(s_raw[0]));
  const float dens = Nb * 1e-4f + Nl * 1e-6f;
  const float eps_v = 1.5f + 20.0f * mg;
  const float Kv    = (eps_v - 1.0f) / (eps_v + 2.0f);
  const float Kv2   = Kv * Kv;

  // ---- thread mapping: 4 lanes per sample = {MLP m} x {k/j half q} ----
  const int g   = blockIdx.x * BLK + tid;
  const int n   = g >> 2;
  const int sub = g & 3;
  const int m   = sub & 1;
  const int q   = sub >> 1;
  const int kh0 = q * 32;   // owned hidden range (layer1 outputs / layer2 j's)

  const float4 xa = reinterpret_cast<const float4*>(X)[n * 2];
  const float4 xb = reinterpret_cast<const float4*>(X)[n * 2 + 1];
  const float xs[8] = { xa.x, xa.y, xa.z, xa.w, xb.x, xb.y, xb.z, xb.w };

  __syncthreads();   // weights staged

  // ---- layer 1: h1[k] for own 32 k's, store to LDS ----
  {
    const float* w1 = &W1s[m][0];
    const float* b1 = &b1s[m][0];
#pragma unroll
    for (int kg = 0; kg < 8; ++kg) {
      const int k = kh0 + kg * 4;
      const float4 bv = *reinterpret_cast<const float4*>(&b1[k]);
      float a0 = bv.x, a1 = bv.y, a2 = bv.z, a3 = bv.w;
#pragma unroll
      for (int i = 0; i < 8; ++i) {
        const float4 wv = *reinterpret_cast<const float4*>(&w1[i * 64 + k]);
        const float xi = xs[i];
        a0 += xi * wv.x; a1 += xi * wv.y; a2 += xi * wv.z; a3 += xi * wv.w;
      }
      float4 hv;
      hv.x = tanh_f(a0); hv.y = tanh_f(a1); hv.z = tanh_f(a2); hv.w = tanh_f(a3);
      *reinterpret_cast<float4*>(&h1s[tid][kg * 4]) = hv;
    }
  }
  __syncthreads();   // h1 visible to the q-partner

  // ---- layer 2: h2[j] for own 32 j's over all 64 k (k<32 from q=0 thread, k>=32 from q=1) ----
  float acc[32];
#pragma unroll
  for (int j = 0; j < 32; ++j) acc[j] = 0.0f;
  {
    const float* w2   = &W2s[m][0];
    const float* h1lo = &h1s[tid & ~2][0];
    const float* h1hi = &h1s[tid |  2][0];

#pragma unroll 2
    for (int kg = 0; kg < 8; ++kg) {
      const float4 hv = *reinterpret_cast<const float4*>(h1lo + kg * 4);
      const float* rb = w2 + (kg * 4) * 64 + kh0;
      const float hvv[4] = { hv.x, hv.y, hv.z, hv.w };
#pragma unroll
      for (int u = 0; u < 4; ++u) {
        const float* row = rb + u * 64;
        const float h = hvv[u];
#pragma unroll
        for (int jg = 0; jg < 8; ++jg) {
          const float4 wv = *reinterpret_cast<const float4*>(row + jg * 4);
          acc[jg*4+0] += h * wv.x; acc[jg*4+1] += h * wv.y;
          acc[jg*4+2] += h * wv.z; acc[jg*4+3] += h * wv.w;
        }
      }
    }
#pragma unroll 2
    for (int kg = 0; kg < 8; ++kg) {
      const float4 hv = *reinterpret_cast<const float4*>(h1hi + kg * 4);
      const float* rb = w2 + (32 + kg * 4) * 64 + kh0;
      const float hvv[4] = { hv.x, hv.y, hv.z, hv.w };
#pragma unroll
      for (int u = 0; u < 4; ++u) {
        const float* row = rb + u * 64;
        const float h = hvv[u];
#pragma unroll
        for (int jg = 0; jg < 8; ++jg) {
          const float4 wv = *reinterpret_cast<const float4*>(row + jg * 4);
          acc[jg*4+0] += h * wv.x; acc[jg*4+1] += h * wv.y;
          acc[jg*4+2] += h * wv.z; acc[jg*4+3] += h * wv.w;
        }
      }
    }
  }

  // ---- layer 3 over own j's, then reduce q (xor 2) and exchange MLPs (xor 1) ----
  float sp0 = 0.f, sp1 = 0.f, sp2 = 0.f, sp3 = 0.f;
  {
    const float* b2 = &b2s[m][0];
    const float* w3 = &W3s[m][0];
#pragma unroll
    for (int jj = 0; jj < 32; jj += 4) {
      const int j = kh0 + jj;
      const float4 bv = *reinterpret_cast<const float4*>(&b2[j]);
      const float4 wv = *reinterpret_cast<const float4*>(&w3[j]);
      sp0 += tanh_f(acc[jj+0] + bv.x) * wv.x;
      sp1 += tanh_f(acc[jj+1] + bv.y) * wv.y;
      sp2 += tanh_f(acc[jj+2] + bv.z) * wv.z;
      sp3 += tanh_f(acc[jj+3] + bv.w) * wv.w;
    }
  }
  float s_own = (sp0 + sp1) + (sp2 + sp3);
  float s_tot = s_own + __shfl_xor(s_own, 2) + b3s[m];
  const float oth  = __shfl_xor(s_tot, 1);
  const float raw_p = m ? oth   : s_tot;
  const float raw_c = m ? s_tot : oth;

  // ---- physics epilogue (all 4 lanes compute; stores split) ----
  const float m_v   = 0.93f * sigmoid_f(raw_p);
  const float delta = 0.05f * tanh_f(raw_c);
  const float m_vf  = m_v + delta;
  const float eps_g = 3.0f + 25.0f * m_v + 10.0f * m_v * m_v;

  const float ti = theta_deg[n] * (PI_F / 180.0f);
  const float ct = cosf(ti), st = sinf(ti);
  const float ct2 = ct * ct, st2 = st * st;

  const float crown_vv = Kv2 * (ct2 * ct2 * S1 + 3.0f * ct2 * st2 * S2 + 0.375f * st2 * st2 * S3);
  const float crown_vh = Kv2 * (0.5f * ct2 * S2 + 0.125f * st2 * S3);

  const float root = sqrtf(eps_g - st2);
  const float egct = eps_g * ct;
  const float r_v  = (egct - root) / (egct + root);
  const float gamma_v = r_v * r_v;
  const float a = 2.0f * K_WAVE_F * smr * ct;
  const float rough = __expf(-a * a);
  const float ground = gamma_v * rough * ct2;

  const float svv = dens * crown_vv + ground;
  const float svh = dens * crown_vh + 0.05f * ground;
  const float vv_db = 10.0f * __log10f(svv + 1e-12f);
  const float vh_db = 10.0f * __log10f(svh + 1e-12f);

  if      (sub == 0) { out[n]              = m_v;   out[4*N_SAMP + n] = vh_db; }
  else if (sub == 1) { out[N_SAMP + n]     = delta; out[5*N_SAMP + n] = eps_g; }
  else if (sub == 2) { out[2*N_SAMP + n]   = m_vf; }
  else               { out[3*N_SAMP + n]   = vv_db; }
}

extern "C" void kernel_launch(void* const* d_in, const int* in_sizes, int n_in,
                              void* d_out, int out_size, void* d_ws, size_t ws_size,
                              hipStream_t stream) {
  const float* X   = (const float*)d_in[0];
  const float* th  = (const float*)d_in[1];
  // d_in[2] = vv_db_observed (unused pass-through)
  const float* Wp1 = (const float*)d_in[3];
  const float* bp1 = (const float*)d_in[4];
  const float* Wp2 = (const float*)d_in[5];
  const float* bp2 = (const float*)d_in[6];
  const float* Wp3 = (const float*)d_in[7];
  const float* bp3 = (const float*)d_in[8];
  const float* Wc1 = (const float*)d_in[9];
  const float* bc1 = (const float*)d_in[10];
  const float* Wc2 = (const float*)d_in[11];
  const float* bc2 = (const float*)d_in[12];
  const float* Wc3 = (const float*)d_in[13];
  const float* bc3 = (const float*)d_in[14];
  const float* nb  = (const float*)d_in[15];
  const float* nl  = (const float*)d_in[16];
  const float* so  = (const float*)d_in[17];
  const float* mg  = (const float*)d_in[18];
  const float* sr  = (const float*)d_in[19];

  dim3 grid(N_SAMP * 4 / BLK), block(BLK);
  pinn_fused<<<grid, block, 0, stream>>>(X, th, Wp1, bp1, Wp2, bp2, Wp3, bp3,
                                         Wc1, bc1, Wc2, bc2, Wc3, bc3,
                                         nb, nl, so, mg, sr, (float*)d_out);
}

// Round 2
// 100.161 us; speedup vs baseline: 1.0810x; 1.0810x over previous
//
#include <hip/hip_runtime.h>
#include <math.h>

#define N_SAMP 8192
#define BLK 256        // 4 waves
#define SPB 32         // samples per block
#define W2S 68         // padded W2 row stride (floats): 272B, 16B-aligned, bank offset 4
#define H1S 36         // padded h1 row stride: 144B, 16B-aligned
#define PSS 20         // padded partial-sum row stride: 80B, 16B-aligned

constexpr float PI_F = 3.14159265358979323846f;
constexpr float K_WAVE_F = (float)(2.0 * 3.14159265358979323846 * 5.405e9 / 2.998e8);

__device__ __forceinline__ float rcp_f(float x)     { return __builtin_amdgcn_rcpf(x); }
__device__ __forceinline__ float sigmoid_f(float x) { return rcp_f(1.0f + __expf(-x)); }
// 1 - 2/(e^{2x}+1): exact saturation at +-inf, ~1e-7 abs error
__device__ __forceinline__ float tanh_f(float x)    { return 1.0f - 2.0f * rcp_f(__expf(2.0f * x) + 1.0f); }

__global__ __launch_bounds__(BLK) void pinn_fused(
    const float* __restrict__ X, const float* __restrict__ theta_deg,
    const float* __restrict__ Wp1, const float* __restrict__ bp1,
    const float* __restrict__ Wp2, const float* __restrict__ bp2,
    const float* __restrict__ Wp3, const float* __restrict__ bp3,
    const float* __restrict__ Wc1, const float* __restrict__ bc1,
    const float* __restrict__ Wc2, const float* __restrict__ bc2,
    const float* __restrict__ Wc3, const float* __restrict__ bc3,
    const float* __restrict__ nb_raw, const float* __restrict__ nl_raw,
    const float* __restrict__ so_raw, const float* __restrict__ mg_raw,
    const float* __restrict__ s_raw, float* __restrict__ out)
{
  __shared__ float Xs[SPB][8];            // 1 KB
  __shared__ float W1s[2][520];           // [m][i*64+k], 4.2 KB
  __shared__ float W2s[2][64 * W2S];      // [m][k*W2S+j], 34.8 KB
  __shared__ float h1s[2][64][H1S];       // [m][k][s] transposed!, 18.4 KB
  __shared__ float b1s[2][64], b2s[2][64], W3s[2][64];
  __shared__ float b3s[2];
  __shared__ float ps[2][SPB][PSS];       // layer-3 partials, 5.1 KB

  const int tid = threadIdx.x;
  const int bs  = blockIdx.x * SPB;       // sample base

  // ---- stage to LDS (coalesced) ----
  if (tid < 64) reinterpret_cast<float4*>(&Xs[0][0])[tid] =
      reinterpret_cast<const float4*>(X + bs * 8)[tid];
  {
    const int mm = tid >> 7, i = (tid & 127);            // 128 float4 per MLP
    const float* src1 = mm ? Wc1 : Wp1;
    reinterpret_cast<float4*>(&W1s[mm][0])[i] = reinterpret_cast<const float4*>(src1)[i];
  }
#pragma unroll
  for (int r = 0; r < 4; ++r) {                          // W2 with padded stride
    const int v = tid + BLK * r;                         // 0..1023 float4 units
    const int k = v >> 4, jq = v & 15;
    *reinterpret_cast<float4*>(&W2s[0][k * W2S + 4 * jq]) =
        reinterpret_cast<const float4*>(Wp2)[v];
    *reinterpret_cast<float4*>(&W2s[1][k * W2S + 4 * jq]) =
        reinterpret_cast<const float4*>(Wc2)[v];
  }
  if (tid < 64) {
    b1s[0][tid] = bp1[tid]; b1s[1][tid] = bc1[tid];
    b2s[0][tid] = bp2[tid]; b2s[1][tid] = bc2[tid];
    W3s[0][tid] = Wp3[tid]; W3s[1][tid] = Wc3[tid];
    if (tid < 2) b3s[tid] = (tid == 0) ? bp3[0] : bc3[0];
  }

  // ---- scalar params + theta-moments: wave 0 only (physics lanes live there) ----
  float S1 = 0.f, S2 = 0.f, S3 = 0.f;
  float Kv2 = 0.f, dens = 0.f, smr = 0.f;
  if (tid < 64) {
    const float sig_o  = (10.0f + 70.0f * sigmoid_f(so_raw[0])) * (PI_F / 180.0f);
    const float inv2s2 = 1.0f / (2.0f * sig_o * sig_o);
    float p0 = 0.f, p1 = 0.f, p2 = 0.f, p3 = 0.f;
#pragma unroll
    for (int r = 0; r < 2; ++r) {
      const int   t   = tid + 64 * r;
      const float th  = (float)t * (PI_F * 0.5f / 127.0f);
      const float snt = sinf(th), cst = cosf(th);
      const float d   = th - PI_F * 0.25f;
      const float pdf = __expf(-d * d * inv2s2) * snt;
      const float c2 = cst * cst, s2 = snt * snt;
      p0 += pdf; p1 += pdf * c2 * c2; p2 += pdf * c2 * s2; p3 += pdf * s2 * s2;
    }
#pragma unroll
    for (int off = 1; off < 64; off <<= 1) {
      p0 += __shfl_xor(p0, off); p1 += __shfl_xor(p1, off);
      p2 += __shfl_xor(p2, off); p3 += __shfl_xor(p3, off);
    }
    const float invp0 = 1.0f / p0;
    S1 = p1 * invp0; S2 = p2 * invp0; S3 = p3 * invp0;

    const float Nb  = exp10f(2.0f + 3.0f * sigmoid_f(nb_raw[0]));
    const float Nl  = exp10f(3.0f + 3.0f * sigmoid_f(nl_raw[0]));
    const float mg  = 0.05f + 0.75f * sigmoid_f(mg_raw[0]);
    smr  = 0.01f * (0.5f + 5.5f * sigmoid_f(s_raw[0]));
    dens = Nb * 1e-4f + Nl * 1e-6f;
    const float eps_v = 1.5f + 20.0f * mg;
    const float Kv    = (eps_v - 1.0f) / (eps_v + 2.0f);
    Kv2 = Kv * Kv;
  }

  __syncthreads();   // staging complete

  // ---- layer 1: thread = (m, 4 k's, 4 samples); h1 stored transposed [m][k][s] ----
  {
    const int m1 = tid >> 7, kq = (tid >> 3) & 15, sp = tid & 7;
    const int k0 = 4 * kq, s0 = 4 * sp;
    float4 xl[4], xh[4];
#pragma unroll
    for (int si = 0; si < 4; ++si) {
      xl[si] = *reinterpret_cast<const float4*>(&Xs[s0 + si][0]);
      xh[si] = *reinterpret_cast<const float4*>(&Xs[s0 + si][4]);
    }
    float h[4][4];
#pragma unroll
    for (int kk = 0; kk < 4; ++kk) {
      const float b = b1s[m1][k0 + kk];
#pragma unroll
      for (int si = 0; si < 4; ++si) h[kk][si] = b;
    }
    float4 wv;
#define L1_STEP(I, ARR, COMP)                                            \
    wv = *reinterpret_cast<const float4*>(&W1s[m1][(I) * 64 + k0]);      \
    h[0][0]+=ARR[0].COMP*wv.x; h[1][0]+=ARR[0].COMP*wv.y; h[2][0]+=ARR[0].COMP*wv.z; h[3][0]+=ARR[0].COMP*wv.w; \
    h[0][1]+=ARR[1].COMP*wv.x; h[1][1]+=ARR[1].COMP*wv.y; h[2][1]+=ARR[1].COMP*wv.z; h[3][1]+=ARR[1].COMP*wv.w; \
    h[0][2]+=ARR[2].COMP*wv.x; h[1][2]+=ARR[2].COMP*wv.y; h[2][2]+=ARR[2].COMP*wv.z; h[3][2]+=ARR[2].COMP*wv.w; \
    h[0][3]+=ARR[3].COMP*wv.x; h[1][3]+=ARR[3].COMP*wv.y; h[2][3]+=ARR[3].COMP*wv.z; h[3][3]+=ARR[3].COMP*wv.w;
    L1_STEP(0, xl, x) L1_STEP(1, xl, y) L1_STEP(2, xl, z) L1_STEP(3, xl, w)
    L1_STEP(4, xh, x) L1_STEP(5, xh, y) L1_STEP(6, xh, z) L1_STEP(7, xh, w)
#undef L1_STEP
#pragma unroll
    for (int kk = 0; kk < 4; ++kk) {
      float4 hv;
      hv.x = tanh_f(h[kk][0]); hv.y = tanh_f(h[kk][1]);
      hv.z = tanh_f(h[kk][2]); hv.w = tanh_f(h[kk][3]);
      *reinterpret_cast<float4*>(&h1s[m1][k0 + kk][s0]) = hv;
    }
  }
  __syncthreads();   // h1 visible

  // ---- layer 2: register-blocked 4s x 4j, k fully unrolled, imm LDS offsets ----
  const int jg = tid & 15, sg = (tid >> 4) & 7, m = tid >> 7;
  float acc[4][4];
#pragma unroll
  for (int a = 0; a < 4; ++a)
#pragma unroll
    for (int b = 0; b < 4; ++b) acc[a][b] = 0.0f;
  {
    const float* w2p = &W2s[m][4 * jg];
    const float* h1p = &h1s[m][0][4 * sg];
#pragma unroll
    for (int k = 0; k < 64; ++k) {
      const float4 wv = *reinterpret_cast<const float4*>(w2p + k * W2S);
      const float4 hv = *reinterpret_cast<const float4*>(h1p + k * H1S);
      acc[0][0] += hv.x * wv.x; acc[0][1] += hv.x * wv.y; acc[0][2] += hv.x * wv.z; acc[0][3] += hv.x * wv.w;
      acc[1][0] += hv.y * wv.x; acc[1][1] += hv.y * wv.y; acc[1][2] += hv.y * wv.z; acc[1][3] += hv.y * wv.w;
      acc[2][0] += hv.z * wv.x; acc[2][1] += hv.z * wv.y; acc[2][2] += hv.z * wv.z; acc[2][3] += hv.z * wv.w;
      acc[3][0] += hv.w * wv.x; acc[3][1] += hv.w * wv.y; acc[3][2] += hv.w * wv.z; acc[3][3] += hv.w * wv.w;
    }
  }

  // ---- layer 3 partials: tanh(h2)·W3 over own 4 j's, per own 4 samples ----
  {
    const float4 bv = *reinterpret_cast<const float4*>(&b2s[m][4 * jg]);
    const float4 wv = *reinterpret_cast<const float4*>(&W3s[m][4 * jg]);
#pragma unroll
    for (int si = 0; si < 4; ++si) {
      const float p = tanh_f(acc[si][0] + bv.x) * wv.x
                    + tanh_f(acc[si][1] + bv.y) * wv.y
                    + tanh_f(acc[si][2] + bv.z) * wv.z
                    + tanh_f(acc[si][3] + bv.w) * wv.w;
      ps[m][4 * sg + si][jg] = p;
    }
  }
  __syncthreads();   // partials visible

  // ---- final reduce + physics: one lane per sample (wave 0 has S1..S3, params) ----
  if (tid < SPB) {
    const int s = tid;
    float4 a0 = *reinterpret_cast<const float4*>(&ps[0][s][0]);
    float4 a1 = *reinterpret_cast<const float4*>(&ps[0][s][4]);
    float4 a2 = *reinterpret_cast<const float4*>(&ps[0][s][8]);
    float4 a3 = *reinterpret_cast<const float4*>(&ps[0][s][12]);
    const float raw_p = ((a0.x+a0.y+a0.z+a0.w) + (a1.x+a1.y+a1.z+a1.w))
                      + ((a2.x+a2.y+a2.z+a2.w) + (a3.x+a3.y+a3.z+a3.w)) + b3s[0];
    a0 = *reinterpret_cast<const float4*>(&ps[1][s][0]);
    a1 = *reinterpret_cast<const float4*>(&ps[1][s][4]);
    a2 = *reinterpret_cast<const float4*>(&ps[1][s][8]);
    a3 = *reinterpret_cast<const float4*>(&ps[1][s][12]);
    const float raw_c = ((a0.x+a0.y+a0.z+a0.w) + (a1.x+a1.y+a1.z+a1.w))
                      + ((a2.x+a2.y+a2.z+a2.w) + (a3.x+a3.y+a3.z+a3.w)) + b3s[1];

    const float m_v   = 0.93f * sigmoid_f(raw_p);
    const float delta = 0.05f * tanh_f(raw_c);
    const float m_vf  = m_v + delta;
    const float eps_g = 3.0f + 25.0f * m_v + 10.0f * m_v * m_v;

    const float ti = theta_deg[bs + s] * (PI_F / 180.0f);
    const float ct = cosf(ti), st = sinf(ti);
    const float ct2 = ct * ct, st2 = st * st;

    const float crown_vv = Kv2 * (ct2 * ct2 * S1 + 3.0f * ct2 * st2 * S2 + 0.375f * st2 * st2 * S3);
    const float crown_vh = Kv2 * (0.5f * ct2 * S2 + 0.125f * st2 * S3);

    const float root = sqrtf(eps_g - st2);
    const float egct = eps_g * ct;
    const float r_v  = (egct - root) / (egct + root);
    const float gamma_v = r_v * r_v;
    const float aa = 2.0f * K_WAVE_F * smr * ct;
    const float rough = __expf(-aa * aa);
    const float ground = gamma_v * rough * ct2;

    const float svv = dens * crown_vv + ground;
    const float svh = dens * crown_vh + 0.05f * ground;
    const float vv_db = 10.0f * __log10f(svv + 1e-12f);
    const float vh_db = 10.0f * __log10f(svh + 1e-12f);

    out[bs + s]              = m_v;
    out[N_SAMP + bs + s]     = delta;
    out[2 * N_SAMP + bs + s] = m_vf;
    out[3 * N_SAMP + bs + s] = vv_db;
    out[4 * N_SAMP + bs + s] = vh_db;
    out[5 * N_SAMP + bs + s] = eps_g;
  }
}

extern "C" void kernel_launch(void* const* d_in, const int* in_sizes, int n_in,
                              void* d_out, int out_size, void* d_ws, size_t ws_size,
                              hipStream_t stream) {
  const float* X   = (const float*)d_in[0];
  const float* th  = (const float*)d_in[1];
  // d_in[2] = vv_db_observed (unused pass-through)
  const float* Wp1 = (const float*)d_in[3];
  const float* bp1 = (const float*)d_in[4];
  const float* Wp2 = (const float*)d_in[5];
  const float* bp2 = (const float*)d_in[6];
  const float* Wp3 = (const float*)d_in[7];
  const float* bp3 = (const float*)d_in[8];
  const float* Wc1 = (const float*)d_in[9];
  const float* bc1 = (const float*)d_in[10];
  const float* Wc2 = (const float*)d_in[11];
  const float* bc2 = (const float*)d_in[12];
  const float* Wc3 = (const float*)d_in[13];
  const float* bc3 = (const float*)d_in[14];
  const float* nb  = (const float*)d_in[15];
  const float* nl  = (const float*)d_in[16];
  const float* so  = (const float*)d_in[17];
  const float* mg  = (const float*)d_in[18];
  const float* sr  = (const float*)d_in[19];

  dim3 grid(N_SAMP / SPB), block(BLK);
  pinn_fused<<<grid, block, 0, stream>>>(X, th, Wp1, bp1, Wp2, bp2, Wp3, bp3,
                                         Wc1, bc1, Wc2, bc2, Wc3, bc3,
                                         nb, nl, so, mg, sr, (float*)d_out);
}